// Round 1
// 496.797 us; speedup vs baseline: 1.1412x; 1.1412x over previous
//
#include <hip/hip_runtime.h>
#include <hip/hip_bf16.h>

typedef __attribute__((ext_vector_type(8))) short bf16x8;
typedef __attribute__((ext_vector_type(4))) float f32x4;
typedef unsigned int u32;
typedef unsigned short u16;

#define NB 65536
#define NKD 512
#define NVD 512

// ---- workspace layout ----
// f32 grad sums   : ws[0 .. 262144)
// f32 colsum(k)   : ws[262144 .. 262656)
// f32 loss sum    : ws[262656]
// bf16 diffT      : byte offset 1056768, 512 x 65536 (64 MiB)
#define WS_COLSUM 262144
#define WS_LOSS   262656
#define WS_DIFFT_BYTES 1056768

// ---- output layout (f32 elements) ----
#define OUT_LOSS 33554432
#define OUT_W    33554433
#define OUT_S    33816577

__device__ inline u32 pkbf2(float a, float b) {
    __hip_bfloat162 h2 = __float22bfloat162_rn(make_float2(a, b));
    u32 r;
    __builtin_memcpy(&r, &h2, 4);
    return r;
}

__device__ inline void async16(const u16* g, u16* l) {
    __builtin_amdgcn_global_load_lds(
        (const __attribute__((address_space(1))) u32*)g,
        (__attribute__((address_space(3))) u32*)l, 16, 0, 0);
}

// =====================================================================
// K1: retrieved = k @ W.T   (128x128 tile, BK=64, bf16 MFMA 16x16x32)
// v2: double-buffered LDS + register prefetch issued AFTER the barrier,
//     so global loads for tile t+1 overlap tile t's MFMA phase.
//     One barrier per iteration (safe: writer of buf b at iter t+1 has
//     passed barrier t => all waves' iter t-1 reads of buf b drained).
// epilogue: write retrieved(fp32), loss partial, diffT(bf16, transposed)
// =====================================================================
#define PA 72    // A/B LDS pitch (shorts): conflict-free b128 frag reads
#define PT 136   // ldsT pitch (shorts): 16B-aligned rows, 2-way writes

__global__ __launch_bounds__(256, 2)
void k1_gemm1(const float* __restrict__ kmat, const float* __restrict__ vmat,
              const float* __restrict__ Wmat, float* __restrict__ out,
              float* __restrict__ ws, u16* __restrict__ diffT) {
    __shared__ u16 sm[36864];      // 2 buffers x 18432: A at +0 (128x72), B at +9216
    __shared__ float lred[4];

    const int tid = threadIdx.x;
    const int bx = blockIdx.x;                  // 2048 blocks
    const int rowtile = bx >> 2, ntile = bx & 3;
    const long b0 = (long)rowtile * 128;
    const int vd0 = ntile * 128;
    const int wv = tid >> 6, lane = tid & 63;
    const int wm = wv & 1, wn = wv >> 1;
    const int col = lane & 15, kg = lane >> 4;

    const int srow = tid >> 4;                  // 0..15
    const int scol = (tid & 15) * 4;            // 0..60

    f32x4 acc[4][4] = {};

    const float* gA = kmat + (b0 + srow) * 512 + scol;
    const float* gB = Wmat + (long)(vd0 + srow) * 512 + scol;

    // prologue: load tile 0 into registers
    float4 ra[8], rb[8];
#pragma unroll
    for (int i = 0; i < 8; ++i) {
        ra[i] = *(const float4*)(gA + (long)i * 16 * 512);
        rb[i] = *(const float4*)(gB + (long)i * 16 * 512);
    }

    for (int it = 0; it < 8; ++it) {
        u16* Ab = sm + (it & 1) * 18432;
        u16* Bb = Ab + 9216;
#pragma unroll
        for (int i = 0; i < 8; ++i) {
            int r = i * 16 + srow;
            *(uint2*)&Ab[r * PA + scol] = make_uint2(pkbf2(ra[i].x, ra[i].y), pkbf2(ra[i].z, ra[i].w));
            *(uint2*)&Bb[r * PA + scol] = make_uint2(pkbf2(rb[i].x, rb[i].y), pkbf2(rb[i].z, rb[i].w));
        }
        __syncthreads();
        // issue next tile's loads AFTER the barrier: they drain only at the
        // NEXT barrier, i.e. they overlap the whole MFMA phase below.
        if (it < 7) {
            gA += 64; gB += 64;
#pragma unroll
            for (int i = 0; i < 8; ++i) {
                ra[i] = *(const float4*)(gA + (long)i * 16 * 512);
                rb[i] = *(const float4*)(gB + (long)i * 16 * 512);
            }
        }
#pragma unroll
        for (int kk = 0; kk < 2; ++kk) {
            bf16x8 af[4], bfr[4];
#pragma unroll
            for (int i = 0; i < 4; ++i)
                af[i] = *(const bf16x8*)&Ab[(wm * 64 + i * 16 + col) * PA + kk * 32 + kg * 8];
#pragma unroll
            for (int j = 0; j < 4; ++j)
                bfr[j] = *(const bf16x8*)&Bb[(wn * 64 + j * 16 + col) * PA + kk * 32 + kg * 8];
#pragma unroll
            for (int i = 0; i < 4; ++i)
#pragma unroll
                for (int j = 0; j < 4; ++j)
                    acc[i][j] = __builtin_amdgcn_mfma_f32_16x16x32_bf16(af[i], bfr[j], acc[i][j], 0, 0, 0);
        }
    }

    __syncthreads();   // protect LDS before ldsT overlay
    u16* smT = sm;     // [128 vd][PT] overlay, 34816 B (inside buffer 0)

    float lossp = 0.f;
    const int rg = lane >> 4;
#pragma unroll
    for (int i = 0; i < 4; ++i) {
#pragma unroll
        for (int j = 0; j < 4; ++j) {
            int r0 = wm * 64 + i * 16 + rg * 4;
            int c  = wn * 64 + j * 16 + col;
            long gb = b0 + r0;
            float dd[4];
#pragma unroll
            for (int r = 0; r < 4; ++r) {
                float rv = acc[i][j][r];
                long gidx = (gb + r) * 512 + vd0 + c;
                out[gidx] = rv;
                float dv = rv - vmat[gidx];
                lossp += dv * dv;
                dd[r] = dv;
            }
            *(u32*)&smT[c * PT + r0]     = pkbf2(dd[0], dd[1]);
            *(u32*)&smT[c * PT + r0 + 2] = pkbf2(dd[2], dd[3]);
        }
    }

#pragma unroll
    for (int m = 32; m; m >>= 1) lossp += __shfl_xor(lossp, m);
    if (lane == 0) lred[wv] = lossp;
    __syncthreads();   // smT filled + lred ready
    if (tid == 0) atomicAdd(&ws[WS_LOSS], lred[0] + lred[1] + lred[2] + lred[3]);

    // diffT write-out: thread -> row c=tid>>1, half h=tid&1 (64 shorts)
    {
        const int c = tid >> 1, h = tid & 1;
        const u16* src = &smT[c * PT + h * 64];
        u16* dst = diffT + ((long)(vd0 + c) << 16) + b0 + h * 64;
#pragma unroll
        for (int q = 0; q < 8; ++q) {
            uint4 t4 = *(const uint4*)(src + q * 8);
            *(uint4*)(dst + q * 8) = t4;
        }
    }
}

// =====================================================================
// K2: grad_sum = diffT @ k  (per-tile 128x128, split-K=32 chunks of 2048)
// v2: double-buffered LDS; A (diffT) staged via global_load_lds into the
//     OTHER buffer right after the barrier (overlaps current MFMAs);
//     B (k fp32) prefetched into registers the same way, packed to bf16
//     at the top of the next iteration. One barrier per iteration.
// vd0==0 blocks also accumulate column sums of k for the gates.
// =====================================================================
__global__ __launch_bounds__(256, 2)
void k2_grad(const u16* __restrict__ diffT, const float* __restrict__ kmat,
             float* __restrict__ ws) {
    __shared__ u16 sm[34816];   // 2 buffers x 17408: As [0,8192) 128x64 unpadded; Bs [8192,17408) 128x72

    const int tid = threadIdx.x;
    const int bx = blockIdx.x;                  // 512 blocks
    const int tile = bx & 15, chunk = bx >> 4;
    const int vd0 = (tile >> 2) * 128, kd0 = (tile & 3) * 128;
    const long b0 = (long)chunk * 2048;
    const int wv = tid >> 6, lane = tid & 63;
    const int wm = wv & 1, wn = wv >> 1;
    const int col = lane & 15, kg = lane >> 4;

    const int bcol = (tid & 63) * 2;            // column pair 0..126
    const int bq = wv * 16;                     // b quarter base

    f32x4 acc[4][4] = {};
    float cs0 = 0.f, cs1 = 0.f;

    const int rowb0 = wv * 32;
    // per-lane global base for A staging (q adds 8<<16, it adds 64)
    const u16* gAit = diffT + ((long)(vd0 + rowb0 + (lane >> 3)) << 16) + b0 + (lane & 7) * 8;
    const float* gk0 = kmat + (b0 + bq) * 512 + kd0 + bcol;

    float2 rB[16];
    // prologue: async-stage A(0) into buf0, load B(0) into registers
#pragma unroll
    for (int q = 0; q < 4; ++q)
        async16(gAit + ((long)(q * 8) << 16), &sm[(rowb0 + q * 8) * 64]);
#pragma unroll
    for (int i = 0; i < 16; ++i) rB[i] = *(const float2*)(gk0 + (long)i * 512);

    for (int it = 0; it < 32; ++it) {
        u16* As = sm + (it & 1) * 17408;
        u16* Bs = As + 8192;
        // pack B(it) into Bs (rB loaded one iteration ago; vmcnt-waited here)
        {
#pragma unroll
            for (int i = 0; i < 16; ++i) { cs0 += rB[i].x; cs1 += rB[i].y; }
            u32 p0[8], p1[8];
#pragma unroll
            for (int i = 0; i < 8; ++i) {
                p0[i] = pkbf2(rB[2 * i].x, rB[2 * i + 1].x);
                p1[i] = pkbf2(rB[2 * i].y, rB[2 * i + 1].y);
            }
            *(uint4*)&Bs[bcol * PA + bq]           = make_uint4(p0[0], p0[1], p0[2], p0[3]);
            *(uint4*)&Bs[bcol * PA + bq + 8]       = make_uint4(p0[4], p0[5], p0[6], p0[7]);
            *(uint4*)&Bs[(bcol + 1) * PA + bq]     = make_uint4(p1[0], p1[1], p1[2], p1[3]);
            *(uint4*)&Bs[(bcol + 1) * PA + bq + 8] = make_uint4(p1[4], p1[5], p1[6], p1[7]);
        }
        __syncthreads();   // As(it) asyncs + Bs(it) writes visible; frees other buffer
        // issue next tile's staging AFTER the barrier -> overlaps MFMAs below
        if (it < 31) {
            u16* An = sm + (((it & 1) ^ 1)) * 17408;
            const u16* gan = gAit + (it + 1) * 64;
#pragma unroll
            for (int q = 0; q < 4; ++q)
                async16(gan + ((long)(q * 8) << 16), &An[(rowb0 + q * 8) * 64]);
            const float* gkn = gk0 + (long)(it + 1) * 64 * 512;
#pragma unroll
            for (int i = 0; i < 16; ++i) rB[i] = *(const float2*)(gkn + (long)i * 512);
        }
#pragma unroll
        for (int kk = 0; kk < 2; ++kk) {
            bf16x8 af[4], bfr[4];
#pragma unroll
            for (int i = 0; i < 4; ++i)
                af[i] = *(const bf16x8*)&As[(wm * 64 + i * 16 + col) * 64 + kk * 32 + kg * 8];
#pragma unroll
            for (int j = 0; j < 4; ++j)
                bfr[j] = *(const bf16x8*)&Bs[(wn * 64 + j * 16 + col) * PA + kk * 32 + kg * 8];
#pragma unroll
            for (int i = 0; i < 4; ++i)
#pragma unroll
                for (int j = 0; j < 4; ++j)
                    acc[i][j] = __builtin_amdgcn_mfma_f32_16x16x32_bf16(af[i], bfr[j], acc[i][j], 0, 0, 0);
        }
    }

    // grad accumulation
    const int rg = lane >> 4;
#pragma unroll
    for (int i = 0; i < 4; ++i)
#pragma unroll
        for (int j = 0; j < 4; ++j)
#pragma unroll
            for (int r = 0; r < 4; ++r) {
                int vd = vd0 + wm * 64 + i * 16 + rg * 4 + r;
                int kd = kd0 + wn * 64 + j * 16 + col;
                atomicAdd(&ws[vd * 512 + kd], acc[i][j][r]);
            }

    // column sums (only one vd-stripe contributes; others read same k but skip)
    if (vd0 == 0) {
        __syncthreads();
        float* cred = (float*)sm;   // [128][4]
        cred[bcol * 4 + wv] = cs0;
        cred[(bcol + 1) * 4 + wv] = cs1;
        __syncthreads();
        if (tid < 128) {
            float s = cred[tid * 4] + cred[tid * 4 + 1] + cred[tid * 4 + 2] + cred[tid * 4 + 3];
            atomicAdd(&ws[WS_COLSUM + kd0 + tid], s);
        }
    }
}

// =====================================================================
// K3: gates + new_W/new_S + loss finalize
// =====================================================================
__global__ __launch_bounds__(256)
void k3_final(const float* __restrict__ Wmat, const float* __restrict__ Smat,
              const float* __restrict__ gw, const float* __restrict__ gb,
              const float* __restrict__ ws, float* __restrict__ out) {
    __shared__ float gates[3];
    const int tid = threadIdx.x;
    if (tid < 64) {
        float d0 = 0.f, d1 = 0.f, d2 = 0.f;
#pragma unroll
        for (int i = 0; i < 8; ++i) {
            int kd = i * 64 + tid;
            float km = ws[WS_COLSUM + kd] * (1.0f / 65536.0f);
            d0 += gw[kd] * km;
            d1 += gw[512 + kd] * km;
            d2 += gw[1024 + kd] * km;
        }
#pragma unroll
        for (int m = 32; m; m >>= 1) {
            d0 += __shfl_xor(d0, m);
            d1 += __shfl_xor(d1, m);
            d2 += __shfl_xor(d2, m);
        }
        if (tid == 0) {
            gates[0] = 1.f / (1.f + __expf(-(d0 + gb[0])));   // alpha
            gates[1] = 1.f / (1.f + __expf(-(d1 + gb[1])));   // eta
            gates[2] = 1.f / (1.f + __expf(-(d2 + gb[2])));   // theta
        }
    }
    __syncthreads();
    const float alpha = gates[0], eta = gates[1], theta = gates[2];
    const int i = blockIdx.x * 256 + tid;
    float g = ws[i] * 5.9604644775390625e-8f;      // 2/(B*VD)
    float ns = eta * Smat[i] - theta * g;
    out[OUT_S + i] = ns;
    out[OUT_W + i] = (1.f - alpha) * Wmat[i] + ns;
    if (blockIdx.x == 0 && tid == 0)
        out[OUT_LOSS] = ws[WS_LOSS] * 2.98023223876953125e-8f;  // 1/(B*VD)
}

extern "C" void kernel_launch(void* const* d_in, const int* in_sizes, int n_in,
                              void* d_out, int out_size, void* d_ws, size_t ws_size,
                              hipStream_t stream) {
    const float* k  = (const float*)d_in[0];
    const float* v  = (const float*)d_in[1];
    const float* W  = (const float*)d_in[2];
    const float* S  = (const float*)d_in[3];
    const float* gw = (const float*)d_in[4];
    const float* gb = (const float*)d_in[5];
    float* out = (float*)d_out;
    float* ws  = (float*)d_ws;
    u16* diffT = (u16*)((char*)d_ws + WS_DIFFT_BYTES);

    // zero grad sums + colsum + loss (ws is re-poisoned to 0xAA each launch)
    hipMemsetAsync(d_ws, 0, (WS_LOSS + 1) * sizeof(float), stream);

    hipLaunchKernelGGL(k1_gemm1, dim3(2048), dim3(256), 0, stream, k, v, W, out, ws, diffT);
    hipLaunchKernelGGL(k2_grad,  dim3(512),  dim3(256), 0, stream, diffT, k, ws);
    hipLaunchKernelGGL(k3_final, dim3(1024), dim3(256), 0, stream, W, S, gw, gb, ws, out);
}